// Round 4
// baseline (9494.812 us; speedup 1.0000x reference)
//
#include <hip/hip_runtime.h>
#include <cstdio>

// HardLSTM (2 layers, T=512, B=32, IN=H=1024) on MI355X.
// Round 4: kill the 128x-redundant LLC broadcast of h. Per-XCD staging:
// 8 elected stager-blocks per XCD copy freshly published h tiles from the
// LLC (bypass loads) into per-XCD scratch via plain L2 write-back stores;
// the other blocks read the A-matrix with plain 16B cached loads from their
// local L2. One acquire-agent fence (buffer_inv, preserves dirty) per block
// per step handles slot-reuse staleness. All cross-XCD traffic stays on
// relaxed agent atomics. Rings shrink to 8 slots.

#define T_STEPS 512
#define BATCH   32
#define HID     1024

typedef __bf16 bf16x8 __attribute__((ext_vector_type(8)));
typedef float  f32x4  __attribute__((ext_vector_type(4)));
typedef unsigned int u32x4 __attribute__((ext_vector_type(4)));
typedef unsigned long long u64;

#define AGLD(p)    __hip_atomic_load((p), __ATOMIC_RELAXED, __HIP_MEMORY_SCOPE_AGENT)
#define AGST(p,v)  __hip_atomic_store((p), (v), __ATOMIC_RELAXED, __HIP_MEMORY_SCOPE_AGENT)

__device__ __forceinline__ unsigned short f2bf(float f){
  union { float f; unsigned u; } v; v.f = f;
  unsigned r = v.u + 0x7FFFu + ((v.u >> 16) & 1u);   // RNE
  return (unsigned short)(r >> 16);
}
__device__ __forceinline__ unsigned umin2(unsigned a, unsigned b){ return a < b ? a : b; }

__device__ __forceinline__ bf16x8 ldg_frag(const unsigned short* p){
  u32x4 v = *reinterpret_cast<const u32x4*>(p);
  return __builtin_bit_cast(bf16x8, v);
}
__device__ __forceinline__ bf16x8 lds_frag(const unsigned short* ldsW, int fi, int lane){
  u32x4 v = *reinterpret_cast<const u32x4*>(ldsW + fi*512 + lane*8);
  return __builtin_bit_cast(bf16x8, v);
}

// global per-block flags (128B-strided), lane-distributed poll
__device__ __forceinline__ void spin_flags(const unsigned int* f, unsigned target, int lane){
  const unsigned int* p0 = f + (size_t)lane*32;
  const unsigned int* p1 = f + (size_t)(lane+64)*32;
  while (true){
    unsigned a = AGLD(p0);
    unsigned b = AGLD(p1);
    if (__all((int)(a >= target && b >= target))) break;
    __builtin_amdgcn_s_sleep(1);
  }
  asm volatile("" ::: "memory");
}

// per-XCD 4-chunk stage flag (4 u32 packed in 16B), uniform poll
__device__ __forceinline__ void spinX(const unsigned int* f, unsigned target){
  const u64* q = reinterpret_cast<const u64*>(f);
  while (true){
    u64 a = AGLD(q);
    u64 b = AGLD(q+1);
    unsigned m = umin2(umin2((unsigned)a, (unsigned)(a>>32)),
                       umin2((unsigned)b, (unsigned)(b>>32)));
    if (m >= target) break;
    __builtin_amdgcn_s_sleep(1);
  }
  asm volatile("" ::: "memory");
}

#define MFMA16 __builtin_amdgcn_mfma_f32_16x16x32_bf16

// ---------------- prep kernels ----------------

__global__ void prep_x(const float* __restrict__ x, unsigned short* __restrict__ xbf, int n8){
  int idx = blockIdx.x*blockDim.x + threadIdx.x;
  int stride = gridDim.x*blockDim.x;
  for (int i = idx; i < n8; i += stride){
    const f32x4* p = reinterpret_cast<const f32x4*>(x + (size_t)i*8);
    f32x4 v0 = p[0], v1 = p[1];
    unsigned u0 = f2bf(v0[0]+1.f) | ((unsigned)f2bf(v0[1]+1.f)<<16);
    unsigned u1 = f2bf(v0[2]+1.f) | ((unsigned)f2bf(v0[3]+1.f)<<16);
    unsigned u2 = f2bf(v1[0]+1.f) | ((unsigned)f2bf(v1[1]+1.f)<<16);
    unsigned u3 = f2bf(v1[2]+1.f) | ((unsigned)f2bf(v1[3]+1.f)<<16);
    u32x4 cv = {u0,u1,u2,u3};
    *reinterpret_cast<u32x4*>(xbf + (size_t)i*8) = cv;
  }
}

__global__ void reduce_mean_f32(const float* __restrict__ src, float* __restrict__ out, float add){
  __shared__ float red[256];
  int t = blockIdx.x, tid = threadIdx.x;
  const float* p = src + (size_t)t*32768;
  float s = 0.f;
  for (int i = tid; i < 32768; i += 256) s += p[i];
  red[tid] = s; __syncthreads();
  for (int o = 128; o > 0; o >>= 1){ if (tid < o) red[tid] += red[tid+o]; __syncthreads(); }
  if (tid == 0) out[t] = red[0]*(1.f/32768.f) + add;
}

__global__ void prep_rs(const float* __restrict__ Wih0, const float* __restrict__ Whh0,
                        const float* __restrict__ Wih1, const float* __restrict__ Whh1,
                        const float* __restrict__ bih0, const float* __restrict__ bhh0,
                        const float* __restrict__ bih1, const float* __restrict__ bhh1,
                        float* __restrict__ rs, float* __restrict__ bias){
  int task = blockIdx.x*4 + (threadIdx.x >> 6);
  int lane = threadIdx.x & 63;
  int L = task >> 12, n = task & 4095;
  const float* pi = (L ? Wih1 : Wih0) + (size_t)n*1024;
  const float* ph = (L ? Whh1 : Whh0) + (size_t)n*1024;
  float s = 0.f;
  #pragma unroll
  for (int e = 0; e < 16; ++e){ int k = lane + e*64; s += pi[k] + ph[k]; }
  #pragma unroll
  for (int m = 32; m; m >>= 1) s += __shfl_xor(s, m);
  if (lane == 0){
    rs[task]   = s;
    bias[task] = (L ? bih1[n] : bih0[n]) + (L ? bhh1[n] : bhh0[n]);
  }
}

__global__ void prep_hinit(const float* __restrict__ h0, unsigned short* __restrict__ hini){
  int i = blockIdx.x*256 + threadIdx.x;  // 65536 = both layers
  hini[i] = f2bf(h0[i]);
}

// ---------------- fused persistent recurrent kernel ----------------
// grid = 256 x 64 (1 block/CU via 128KB LDS -> exactly 32 blocks per XCD).
// Blocks 0..127: layer 0; 128..255: layer 1 (1 step behind).
// Per XCD: elected ranks 0-3 stage Ring0 chunks, ranks 4-7 stage Ring1 chunks
// into per-XCD scratch (plain L2 stores); everyone reads A-matrices from L2.
__global__ __launch_bounds__(64) void rec_fused(
    const unsigned short* __restrict__ Xbf,    // [512][32][1024] bf16 (x+1)
    const unsigned short* __restrict__ Hini,   // [2][32][1024] bf16
    unsigned short* __restrict__ Ring0,        // [8][32768] layer-0 h (= y0)
    unsigned short* __restrict__ Ring1,        // [8][32768] layer-1 h
    float* __restrict__ out,                   // y1 + hn[2][32768] + cn[2][32768]
    const float* __restrict__ Wih0, const float* __restrict__ Whh0,
    const float* __restrict__ Wih1, const float* __restrict__ Whh1,
    const float* __restrict__ biasC, const float* __restrict__ rsC,   // [2*4096]
    const float* __restrict__ eps0,            // [512]
    const float* __restrict__ c0,              // [2][32][1024]
    unsigned int* __restrict__ flag0,          // [128] u32, 128B-strided
    unsigned int* __restrict__ flag1,          // [128] u32, 128B-strided
    unsigned int* __restrict__ xcdFlag,        // [8 xcc][2 stream][32] u32
    unsigned int* __restrict__ elect,          // [8 xcc][32] u32
    int* __restrict__ epsP,                    // [512][128] i32 dense
    unsigned short* __restrict__ xscr)         // [8 xcc][2][8 slot][32768]
{
  __shared__ unsigned short ldsW[65536];       // fragment-linear W slice
  const int lane = threadIdx.x;
  const int L    = blockIdx.x >> 7;
  const int bid  = blockIdx.x & 127;
  const int jb   = bid * 8;
  const int l15  = lane & 15;
  const int koff = (lane >> 4) << 3;
  const bool isLow = (l15 < 8);

  // ---- XCD identity + stager election ----
  unsigned xcc;
  asm volatile("s_getreg_b32 %0, hwreg(HW_REG_XCC_ID)" : "=s"(xcc));
  xcc &= 7;
  unsigned rank = 0;
  if (lane == 0)
    rank = __hip_atomic_fetch_add(elect + xcc*32, 1u, __ATOMIC_RELAXED, __HIP_MEMORY_SCOPE_AGENT);
  rank = (unsigned)__shfl((int)rank, 0);
  const bool isA = rank < 4;
  const bool isB = (rank >= 4) && (rank < 8);
  const int  chunk = isA ? (int)rank : (int)rank - 4;
  unsigned short* scr0 = xscr + ((size_t)xcc*2 + 0)*8*32768;
  unsigned short* scr1 = xscr + ((size_t)xcc*2 + 1)*8*32768;
  unsigned int* xcdF0 = xcdFlag + (xcc*2 + 0)*32;
  unsigned int* xcdF1 = xcdFlag + (xcc*2 + 1)*32;

  const float* Wih = L ? Wih1 : Wih0;
  const float* Whh = L ? Whh1 : Whh0;

  // ---- stage W slice into LDS (fp32 -> bf16, fragment-linear) ----
  for (int fi = 0; fi < 128; ++fi){
    int ktg = fi >> 1, nt = fi & 1;
    int r = nt*16 + l15;
    int n = (r >> 3)*1024 + jb + (r & 7);
    int k0 = ktg*32 + koff;
    const float* src = (k0 < 1024) ? (Wih + (size_t)n*1024 + k0)
                                   : (Whh + (size_t)n*1024 + (k0 - 1024));
    f32x4 w0 = *reinterpret_cast<const f32x4*>(src);
    f32x4 w1 = *reinterpret_cast<const f32x4*>(src + 4);
    unsigned u0 = f2bf(w0[0]) | ((unsigned)f2bf(w0[1])<<16);
    unsigned u1 = f2bf(w0[2]) | ((unsigned)f2bf(w0[3])<<16);
    unsigned u2 = f2bf(w1[0]) | ((unsigned)f2bf(w1[1])<<16);
    unsigned u3 = f2bf(w1[2]) | ((unsigned)f2bf(w1[3])<<16);
    u32x4 cv = {u0,u1,u2,u3};
    *reinterpret_cast<u32x4*>(&ldsW[fi*512 + lane*8]) = cv;
  }

  int c0s = l15, c1s = 16 + l15;
  int n0 = L*4096 + (c0s >> 3)*1024 + jb + (c0s & 7);
  int n1 = L*4096 + (c1s >> 3)*1024 + jb + (c1s & 7);
  float bia0 = biasC[n0], rsv0 = rsC[n0];
  float bia1 = biasC[n1], rsv1 = rsC[n1];

  const int bq = (lane >> 4) * 4;
  const int jw = jb + (lane & 7);
  float creg[2][4];
  #pragma unroll
  for (int m = 0; m < 2; ++m)
    #pragma unroll
    for (int r = 0; r < 4; ++r)
      creg[m][r] = c0[L*32768 + (m*16 + bq + r)*1024 + jw];

  float* outHn = out + 16777216 + L*32768;
  float* outCn = out + 16777216 + 65536 + L*32768;
  unsigned int* myflag = (L ? flag1 : flag0) + (size_t)bid*32;

  // ---- stager copy: 16KB chunk, bypass-read Ring -> plain-store scratch ----
  auto stage_copy = [&](const unsigned short* srcSlot, unsigned short* dstSlot){
    const u64* src = reinterpret_cast<const u64*>(srcSlot + chunk*8192);
    unsigned short* dst = dstSlot + chunk*8192;
    #pragma unroll
    for (int it = 0; it < 16; ++it){
      int idx = it*64 + lane;                 // 16B units
      u64 v0 = AGLD(src + idx*2);
      u64 v1 = AGLD(src + idx*2 + 1);
      u32x4 w = {(unsigned)v0, (unsigned)(v0>>32), (unsigned)v1, (unsigned)(v1>>32)};
      *reinterpret_cast<u32x4*>(dst + idx*8) = w;
    }
  };
  auto stageA = [&](int s){
    if (s < 0) return;
    spin_flags(flag0, (unsigned)(s+1), lane);            // Ring0[s] complete
    if (s >= 7) spin_flags(flag1, (unsigned)(s-6), lane); // slot/ring reuse safe
    stage_copy(Ring0 + (size_t)(s&7)*32768, scr0 + (size_t)(s&7)*32768);
    asm volatile("s_waitcnt vmcnt(0)" ::: "memory");
    if (lane == 0) AGST(xcdF0 + chunk, (unsigned)(s+1));
  };
  auto stageB = [&](int s){
    if (s < 0) return;
    spin_flags(flag1, (unsigned)(s+1), lane);            // Ring1[s] complete (covers reuse)
    stage_copy(Ring1 + (size_t)(s&7)*32768, scr1 + (size_t)(s&7)*32768);
    asm volatile("s_waitcnt vmcnt(0)" ::: "memory");
    if (lane == 0) AGST(xcdF1 + chunk, (unsigned)(s+1));
  };

  for (int t = 0; t < T_STEPS; ++t){
    // ---- staging duties (unblock this XCD first) ----
    if (isA) stageA(L ? t     : t-1);
    if (isB) stageB(L ? t-1   : t-2);

    f32x4 acc00 = {0.f,0.f,0.f,0.f}, acc01 = {0.f,0.f,0.f,0.f};
    f32x4 acc10 = {0.f,0.f,0.f,0.f}, acc11 = {0.f,0.f,0.f,0.f};
    float et;

    if (L == 0){
      // x-projection (independent of h) first
      const unsigned short* A0 = Xbf + (size_t)t*32768 + l15*HID + koff;
      #pragma unroll 4
      for (int kt = 0; kt < 32; ++kt){
        bf16x8 a0 = ldg_frag(A0 + kt*32);
        bf16x8 a1 = ldg_frag(A0 + 16*HID + kt*32);
        bf16x8 b0 = lds_frag(ldsW, kt*2 + 0, lane);
        bf16x8 b1 = lds_frag(ldsW, kt*2 + 1, lane);
        acc00 = MFMA16(a0, b0, acc00, 0, 0, 0);
        acc01 = MFMA16(a0, b1, acc01, 0, 0, 0);
        acc10 = MFMA16(a1, b0, acc10, 0, 0, 0);
        acc11 = MFMA16(a1, b1, acc11, 0, 0, 0);
      }
      et = eps0[t];
      if (t > 0){
        spinX(xcdF0, (unsigned)t);                       // scratch0 slot t-1 staged
        __builtin_amdgcn_fence(__ATOMIC_ACQUIRE, "agent");
      }
      const unsigned short* Ah = ((t == 0) ? Hini : scr0 + (size_t)((t-1)&7)*32768)
                                 + l15*HID + koff;
      #pragma unroll 4
      for (int kt = 0; kt < 32; ++kt){
        bf16x8 a0 = ldg_frag(Ah + kt*32);
        bf16x8 a1 = ldg_frag(Ah + 16*HID + kt*32);
        bf16x8 b0 = lds_frag(ldsW, (32+kt)*2 + 0, lane);
        bf16x8 b1 = lds_frag(ldsW, (32+kt)*2 + 1, lane);
        acc00 = MFMA16(a0, b0, acc00, 0, 0, 0);
        acc01 = MFMA16(a0, b1, acc01, 0, 0, 0);
        acc10 = MFMA16(a1, b0, acc10, 0, 0, 0);
        acc11 = MFMA16(a1, b1, acc11, 0, 0, 0);
      }
    } else {
      // own-h half (early dependency)
      if (t > 0){
        spinX(xcdF1, (unsigned)t);                       // scratch1 slot t-1 staged
        __builtin_amdgcn_fence(__ATOMIC_ACQUIRE, "agent");
      }
      const unsigned short* Ah = ((t == 0) ? Hini + 32768 : scr1 + (size_t)((t-1)&7)*32768)
                                 + l15*HID + koff;
      #pragma unroll 4
      for (int kt = 0; kt < 32; ++kt){
        bf16x8 a0 = ldg_frag(Ah + kt*32);
        bf16x8 a1 = ldg_frag(Ah + 16*HID + kt*32);
        bf16x8 b0 = lds_frag(ldsW, (32+kt)*2 + 0, lane);
        bf16x8 b1 = lds_frag(ldsW, (32+kt)*2 + 1, lane);
        acc00 = MFMA16(a0, b0, acc00, 0, 0, 0);
        acc01 = MFMA16(a0, b1, acc01, 0, 0, 0);
        acc10 = MFMA16(a1, b0, acc10, 0, 0, 0);
        acc11 = MFMA16(a1, b1, acc11, 0, 0, 0);
      }
      spinX(xcdF0, (unsigned)(t+1));                     // scratch0 slot t (y0[t]) staged
      // eps1[t]: exact fixed-point sum of 128 per-block partials
      {
        const u64* ep = reinterpret_cast<const u64*>(epsP + (size_t)t*128);
        u64 v = AGLD(ep + lane);
        int s = (int)(unsigned)v + (int)(unsigned)(v >> 32);
        #pragma unroll
        for (int mm = 32; mm; mm >>= 1) s += __shfl_xor(s, mm);
        et = (float)s * 4.6566128730773926e-10f;         // / (2^16 * 32768)
      }
      const unsigned short* Ay = scr0 + (size_t)(t&7)*32768 + l15*HID + koff;
      #pragma unroll 4
      for (int kt = 0; kt < 32; ++kt){
        bf16x8 a0 = ldg_frag(Ay + kt*32);
        bf16x8 a1 = ldg_frag(Ay + 16*HID + kt*32);
        bf16x8 b0 = lds_frag(ldsW, kt*2 + 0, lane);
        bf16x8 b1 = lds_frag(ldsW, kt*2 + 1, lane);
        acc00 = MFMA16(a0, b0, acc00, 0, 0, 0);
        acc01 = MFMA16(a0, b1, acc01, 0, 0, 0);
        acc10 = MFMA16(a1, b0, acc10, 0, 0, 0);
        acc11 = MFMA16(a1, b1, acc11, 0, 0, 0);
      }
    }

    // ---- epilogue ----
    unsigned short* ring = (L ? Ring1 : Ring0) + (size_t)(t & 7)*32768;
    float psum = 0.f;
    #pragma unroll
    for (int m = 0; m < 2; ++m){
      f32x4 ga = m ? acc10 : acc00;   // cols 0..7 = i, 8..15 = f
      f32x4 gb = m ? acc11 : acc01;   // cols 16..23 = g, 24..31 = o
      #pragma unroll
      for (int r = 0; r < 4; ++r){
        float g0 = ga[r] + bia0 + et*rsv0;
        float g1 = gb[r] + bia1 + et*rsv1;
        float p0 = __shfl_xor(g0, 8);
        float p1 = __shfl_xor(g1, 8);
        float iv = isLow ? g0 : p0;
        float fv = isLow ? p0 : g0;
        float gv = isLow ? g1 : p1;
        float ov = isLow ? p1 : g1;
        iv = fminf(fmaxf(0.2f*iv + 0.5f, 0.f), 1.f);
        fv = fminf(fmaxf(0.2f*fv + 0.5f, 0.f), 1.f);
        gv = fminf(fmaxf(gv, -1.f), 1.f);
        ov = fminf(fmaxf(0.2f*ov + 0.5f, 0.f), 1.f);
        float cc = fv*(creg[m][r] + et) + iv*gv;
        creg[m][r] = cc;
        float hy = ov * fminf(fmaxf(cc, -1.f), 1.f);

        int b = m*16 + bq + r;
        unsigned short hu = f2bf(hy);
        unsigned p2 = (unsigned)hu | (((unsigned)__shfl_xor((int)hu, 1)) << 16);
        unsigned q2 = (unsigned)__shfl_xor((int)p2, 2);
        float f1 = __shfl_xor(hy, 1);
        float f2 = __shfl_xor(hy, 2);
        float f3 = __shfl_xor(f1, 2);
        if (isLow){
          if (!(lane & 3)){
            u64 w = (u64)p2 | ((u64)q2 << 32);           // 4 bf16 cols, LLC write-through
            AGST(reinterpret_cast<u64*>(ring + b*HID + jw), w);
            if (L){
              f32x4 o4 = {hy, f1, f2, f3};
              *reinterpret_cast<f32x4*>(out + (size_t)t*32768 + b*HID + jw) = o4;
            }
          }
          if (L == 0) psum += hy;
          if (t == T_STEPS-1){
            outHn[b*HID + jw] = hy;
            outCn[b*HID + jw] = cc;
          }
        }
      }
    }

    if (L == 0){
      #pragma unroll
      for (int mm = 32; mm; mm >>= 1) psum += __shfl_xor(psum, mm);
      if (lane == 0)
        AGST(reinterpret_cast<unsigned*>(epsP + (size_t)t*128 + bid),
             (unsigned)(int)llrintf(psum * 65536.f));
    }

    asm volatile("s_waitcnt vmcnt(0)" ::: "memory");     // drain publishes
    if (lane == 0) AGST(myflag, (unsigned)(t+1));
  }

  // L0-flavored stagers must cover the slots L1's last steps consume
  if (L == 0 && isA) stageA(T_STEPS-1);
  if (L == 0 && isB) stageB(T_STEPS-2);
}

// ---------------- host ----------------

extern "C" void kernel_launch(void* const* d_in, const int* in_sizes, int n_in,
                              void* d_out, int out_size, void* d_ws, size_t ws_size,
                              hipStream_t stream)
{
  const float* x    = (const float*)d_in[0];
  const float* h0   = (const float*)d_in[1];
  const float* c0   = (const float*)d_in[2];
  const float* Wih0 = (const float*)d_in[3];
  const float* Whh0 = (const float*)d_in[4];
  const float* bih0 = (const float*)d_in[5];
  const float* bhh0 = (const float*)d_in[6];
  const float* Wih1 = (const float*)d_in[7];
  const float* Whh1 = (const float*)d_in[8];
  const float* bih1 = (const float*)d_in[9];
  const float* bhh1 = (const float*)d_in[10];
  float* out = (float*)d_out;

  char* ws = (char*)d_ws;
  size_t off = 0;
  auto alloc = [&](size_t bytes)->char* {
    char* p = ws + off; off += (bytes + 255) & ~(size_t)255; return p;
  };
  unsigned short* Xbf   = (unsigned short*)alloc((size_t)T_STEPS*BATCH*HID*2); // 32MB
  unsigned short* Ring0 = (unsigned short*)alloc((size_t)8*BATCH*HID*2);       // 512KB
  unsigned short* Ring1 = (unsigned short*)alloc((size_t)8*BATCH*HID*2);       // 512KB
  unsigned short* Hini  = (unsigned short*)alloc((size_t)2*BATCH*HID*2);
  unsigned short* xscr  = (unsigned short*)alloc((size_t)8*2*8*BATCH*HID*2);   // 8MB
  float* eps0 = (float*)alloc(T_STEPS*4);
  float* bias = (float*)alloc(2*4096*4);
  float* rs   = (float*)alloc(2*4096*4);
  int*   epsP = (int*)alloc((size_t)T_STEPS*128*4);                            // 256KB (no init needed)
  // zeroed-per-launch sync area: flag0, flag1 (128 lines each), xcdFlag, elect
  size_t syncBytes = 128*128*2 + 8*2*32*4 + 8*32*4;
  char* sync = alloc(syncBytes);
  unsigned int* flag0   = (unsigned int*)sync;
  unsigned int* flag1   = (unsigned int*)(sync + 128*128);
  unsigned int* xcdFlag = (unsigned int*)(sync + 128*128*2);
  unsigned int* elect   = (unsigned int*)(sync + 128*128*2 + 8*2*32*4);
  if (off > ws_size)
    fprintf(stderr, "HardLSTM: ws too small, need %zu have %zu\n", off, ws_size);

  hipMemsetAsync(sync, 0, syncBytes, stream);
  prep_x<<<4096, 256, 0, stream>>>(x, Xbf, (T_STEPS*BATCH*HID)/8);
  reduce_mean_f32<<<T_STEPS, 256, 0, stream>>>(x, eps0, 1.0f);   // eps0 = mean(x_t)+1
  prep_rs<<<2048, 256, 0, stream>>>(Wih0, Whh0, Wih1, Whh1, bih0, bhh0, bih1, bhh1, rs, bias);
  prep_hinit<<<256, 256, 0, stream>>>(h0, Hini);

  rec_fused<<<256, 64, 0, stream>>>(Xbf, Hini, Ring0, Ring1, out,
      Wih0, Whh0, Wih1, Whh1, bias, rs, eps0, c0,
      flag0, flag1, xcdFlag, elect, epsP, xscr);
}

// Round 5
// 8516.031 us; speedup vs baseline: 1.1149x; 1.1149x over previous
//
#include <hip/hip_runtime.h>
#include <cstdio>

// HardLSTM (2 layers, T=512, B=32, IN=H=1024) on MI355X.
// Round 5: A/B on the spin primitive. r3 structure (direct LLC consume, no
// stager hop), but (1) HOT spin — no s_sleep — with flags packed 2-per-128B
// line so ONE u64 gather per wave polls all 128 flags; (2) epilogue reordered
// so only ring+epsP stores precede the vmcnt(0) drain + flag publish; d_out /
// hn / cn stores happen after the flag (off the critical cycle).

#define T_STEPS 512
#define BATCH   32
#define HID     1024

typedef __bf16 bf16x8 __attribute__((ext_vector_type(8)));
typedef float  f32x4  __attribute__((ext_vector_type(4)));
typedef unsigned int u32x4 __attribute__((ext_vector_type(4)));
typedef unsigned long long u64;

#define AGLD(p)    __hip_atomic_load((p), __ATOMIC_RELAXED, __HIP_MEMORY_SCOPE_AGENT)
#define AGST(p,v)  __hip_atomic_store((p), (v), __ATOMIC_RELAXED, __HIP_MEMORY_SCOPE_AGENT)

__device__ __forceinline__ unsigned short f2bf(float f){
  union { float f; unsigned u; } v; v.f = f;
  unsigned r = v.u + 0x7FFFu + ((v.u >> 16) & 1u);   // RNE
  return (unsigned short)(r >> 16);
}

__device__ __forceinline__ bf16x8 ldg_frag(const unsigned short* p){
  u32x4 v = *reinterpret_cast<const u32x4*>(p);
  return __builtin_bit_cast(bf16x8, v);
}
// LLC-coherent 16B fragment load (bypasses stale L1/L2; pipelined by vmcnt).
__device__ __forceinline__ bf16x8 ldA(const unsigned short* p){
  const u64* q = reinterpret_cast<const u64*>(p);
  u64 v0 = AGLD(q);
  u64 v1 = AGLD(q + 1);
  union { u64 u[2]; bf16x8 f; } w; w.u[0] = v0; w.u[1] = v1; return w.f;
}
__device__ __forceinline__ bf16x8 lds_frag(const unsigned short* ldsW, int fi, int lane){
  u32x4 v = *reinterpret_cast<const u32x4*>(ldsW + fi*512 + lane*8);
  return __builtin_bit_cast(bf16x8, v);
}

// 128 flags packed 2 per 128B line (u32 at +0 and +4). Lane i hot-polls line i
// with one u64 load -> one gather covers all 128 flags. NO s_sleep.
__device__ __forceinline__ void spin_flags(const unsigned int* f, unsigned target, int lane){
  const u64* p = reinterpret_cast<const u64*>(f) + (size_t)lane*16;   // 128B stride
  while (true){
    u64 v = AGLD(p);
    unsigned a = (unsigned)v, b = (unsigned)(v >> 32);
    if (__all((int)(a >= target && b >= target))) break;
  }
  asm volatile("" ::: "memory");   // keep data loads below the spin
}

#define MFMA16 __builtin_amdgcn_mfma_f32_16x16x32_bf16

// ---------------- prep kernels ----------------

__global__ void prep_x(const float* __restrict__ x, unsigned short* __restrict__ xbf, int n8){
  int idx = blockIdx.x*blockDim.x + threadIdx.x;
  int stride = gridDim.x*blockDim.x;
  for (int i = idx; i < n8; i += stride){
    const f32x4* p = reinterpret_cast<const f32x4*>(x + (size_t)i*8);
    f32x4 v0 = p[0], v1 = p[1];
    unsigned u0 = f2bf(v0[0]+1.f) | ((unsigned)f2bf(v0[1]+1.f)<<16);
    unsigned u1 = f2bf(v0[2]+1.f) | ((unsigned)f2bf(v0[3]+1.f)<<16);
    unsigned u2 = f2bf(v1[0]+1.f) | ((unsigned)f2bf(v1[1]+1.f)<<16);
    unsigned u3 = f2bf(v1[2]+1.f) | ((unsigned)f2bf(v1[3]+1.f)<<16);
    u32x4 cv = {u0,u1,u2,u3};
    *reinterpret_cast<u32x4*>(xbf + (size_t)i*8) = cv;
  }
}

__global__ void reduce_mean_f32(const float* __restrict__ src, float* __restrict__ out, float add){
  __shared__ float red[256];
  int t = blockIdx.x, tid = threadIdx.x;
  const float* p = src + (size_t)t*32768;
  float s = 0.f;
  for (int i = tid; i < 32768; i += 256) s += p[i];
  red[tid] = s; __syncthreads();
  for (int o = 128; o > 0; o >>= 1){ if (tid < o) red[tid] += red[tid+o]; __syncthreads(); }
  if (tid == 0) out[t] = red[0]*(1.f/32768.f) + add;
}

__global__ void prep_rs(const float* __restrict__ Wih0, const float* __restrict__ Whh0,
                        const float* __restrict__ Wih1, const float* __restrict__ Whh1,
                        const float* __restrict__ bih0, const float* __restrict__ bhh0,
                        const float* __restrict__ bih1, const float* __restrict__ bhh1,
                        float* __restrict__ rs, float* __restrict__ bias){
  int task = blockIdx.x*4 + (threadIdx.x >> 6);
  int lane = threadIdx.x & 63;
  int L = task >> 12, n = task & 4095;
  const float* pi = (L ? Wih1 : Wih0) + (size_t)n*1024;
  const float* ph = (L ? Whh1 : Whh0) + (size_t)n*1024;
  float s = 0.f;
  #pragma unroll
  for (int e = 0; e < 16; ++e){ int k = lane + e*64; s += pi[k] + ph[k]; }
  #pragma unroll
  for (int m = 32; m; m >>= 1) s += __shfl_xor(s, m);
  if (lane == 0){
    rs[task]   = s;
    bias[task] = (L ? bih1[n] : bih0[n]) + (L ? bhh1[n] : bhh0[n]);
  }
}

__global__ void prep_hinit(const float* __restrict__ h0, unsigned short* __restrict__ hini){
  int i = blockIdx.x*256 + threadIdx.x;  // 65536 = both layers
  hini[i] = f2bf(h0[i]);
}

// ---------------- fused persistent recurrent kernel ----------------
// grid = 256 x 64 (1 block/CU via 128KB LDS). Blocks 0..127: layer 0;
// 128..255: layer 1 (1 step behind). Block owns 8 h-cols x 4 gates.
__global__ __launch_bounds__(64) void rec_fused(
    const unsigned short* __restrict__ Xbf,    // [512][32][1024] bf16 (x+1)
    const unsigned short* __restrict__ Hini,   // [2][32][1024] bf16
    unsigned short* __restrict__ Ring0,        // [512][32768] layer-0 h (= y0)
    unsigned short* __restrict__ Ring1,        // [8][32768]   layer-1 h
    float* __restrict__ out,                   // y1 + hn[2][32768] + cn[2][32768]
    const float* __restrict__ Wih0, const float* __restrict__ Whh0,
    const float* __restrict__ Wih1, const float* __restrict__ Whh1,
    const float* __restrict__ biasC, const float* __restrict__ rsC,   // [2*4096]
    const float* __restrict__ eps0,            // [512]
    const float* __restrict__ c0,              // [2][32][1024]
    unsigned int* __restrict__ flag0,          // 64 lines x 128B (2 flags/line)
    unsigned int* __restrict__ flag1,
    int* __restrict__ epsP)                    // [512][128] i32 dense
{
  __shared__ unsigned short ldsW[65536];       // fragment-linear W slice
  const int lane = threadIdx.x;
  const int L    = blockIdx.x >> 7;
  const int bid  = blockIdx.x & 127;
  const int jb   = bid * 8;
  const int l15  = lane & 15;
  const int koff = (lane >> 4) << 3;
  const bool isLow = (l15 < 8);

  const float* Wih = L ? Wih1 : Wih0;
  const float* Whh = L ? Whh1 : Whh0;

  // ---- stage W slice into LDS (fp32 -> bf16, fragment-linear) ----
  for (int fi = 0; fi < 128; ++fi){
    int ktg = fi >> 1, nt = fi & 1;
    int r = nt*16 + l15;
    int n = (r >> 3)*1024 + jb + (r & 7);
    int k0 = ktg*32 + koff;
    const float* src = (k0 < 1024) ? (Wih + (size_t)n*1024 + k0)
                                   : (Whh + (size_t)n*1024 + (k0 - 1024));
    f32x4 w0 = *reinterpret_cast<const f32x4*>(src);
    f32x4 w1 = *reinterpret_cast<const f32x4*>(src + 4);
    unsigned u0 = f2bf(w0[0]) | ((unsigned)f2bf(w0[1])<<16);
    unsigned u1 = f2bf(w0[2]) | ((unsigned)f2bf(w0[3])<<16);
    unsigned u2 = f2bf(w1[0]) | ((unsigned)f2bf(w1[1])<<16);
    unsigned u3 = f2bf(w1[2]) | ((unsigned)f2bf(w1[3])<<16);
    u32x4 cv = {u0,u1,u2,u3};
    *reinterpret_cast<u32x4*>(&ldsW[fi*512 + lane*8]) = cv;
  }

  int c0s = l15, c1s = 16 + l15;
  int n0 = L*4096 + (c0s >> 3)*1024 + jb + (c0s & 7);
  int n1 = L*4096 + (c1s >> 3)*1024 + jb + (c1s & 7);
  float bia0 = biasC[n0], rsv0 = rsC[n0];
  float bia1 = biasC[n1], rsv1 = rsC[n1];

  const int bq = (lane >> 4) * 4;
  const int jw = jb + (lane & 7);
  float creg[2][4];
  #pragma unroll
  for (int m = 0; m < 2; ++m)
    #pragma unroll
    for (int r = 0; r < 4; ++r)
      creg[m][r] = c0[L*32768 + (m*16 + bq + r)*1024 + jw];

  float* outHn = out + 16777216 + L*32768;
  float* outCn = out + 16777216 + 65536 + L*32768;
  // flag bid lives at line (bid>>1), u32 offset (bid&1)
  unsigned int* myflag = (L ? flag1 : flag0) + (size_t)(bid >> 1)*32 + (bid & 1);

  for (int t = 0; t < T_STEPS; ++t){
    f32x4 acc00 = {0.f,0.f,0.f,0.f}, acc01 = {0.f,0.f,0.f,0.f};
    f32x4 acc10 = {0.f,0.f,0.f,0.f}, acc11 = {0.f,0.f,0.f,0.f};
    float et;

    if (L == 0){
      // x-projection (independent of h) BEFORE the spin
      const unsigned short* A0 = Xbf + (size_t)t*32768 + l15*HID + koff;
      #pragma unroll 4
      for (int kt = 0; kt < 32; ++kt){
        bf16x8 a0 = ldg_frag(A0 + kt*32);
        bf16x8 a1 = ldg_frag(A0 + 16*HID + kt*32);
        bf16x8 b0 = lds_frag(ldsW, kt*2 + 0, lane);
        bf16x8 b1 = lds_frag(ldsW, kt*2 + 1, lane);
        acc00 = MFMA16(a0, b0, acc00, 0, 0, 0);
        acc01 = MFMA16(a0, b1, acc01, 0, 0, 0);
        acc10 = MFMA16(a1, b0, acc10, 0, 0, 0);
        acc11 = MFMA16(a1, b1, acc11, 0, 0, 0);
      }
      et = eps0[t];
      if (t > 0) spin_flags(flag0, (unsigned)t, lane);
      const unsigned short* Ah = ((t == 0) ? Hini : Ring0 + (size_t)(t-1)*32768)
                                 + l15*HID + koff;
      #pragma unroll 4
      for (int kt = 0; kt < 32; ++kt){
        bf16x8 a0 = ldA(Ah + kt*32);
        bf16x8 a1 = ldA(Ah + 16*HID + kt*32);
        bf16x8 b0 = lds_frag(ldsW, (32+kt)*2 + 0, lane);
        bf16x8 b1 = lds_frag(ldsW, (32+kt)*2 + 1, lane);
        acc00 = MFMA16(a0, b0, acc00, 0, 0, 0);
        acc01 = MFMA16(a0, b1, acc01, 0, 0, 0);
        acc10 = MFMA16(a1, b0, acc10, 0, 0, 0);
        acc11 = MFMA16(a1, b1, acc11, 0, 0, 0);
      }
    } else {
      // layer 1: own-h half first
      if (t > 0) spin_flags(flag1, (unsigned)t, lane);
      const unsigned short* Ah = ((t == 0) ? Hini + 32768 : Ring1 + (size_t)((t-1)&7)*32768)
                                 + l15*HID + koff;
      #pragma unroll 4
      for (int kt = 0; kt < 32; ++kt){
        bf16x8 a0 = ldA(Ah + kt*32);
        bf16x8 a1 = ldA(Ah + 16*HID + kt*32);
        bf16x8 b0 = lds_frag(ldsW, (32+kt)*2 + 0, lane);
        bf16x8 b1 = lds_frag(ldsW, (32+kt)*2 + 1, lane);
        acc00 = MFMA16(a0, b0, acc00, 0, 0, 0);
        acc01 = MFMA16(a0, b1, acc01, 0, 0, 0);
        acc10 = MFMA16(a1, b0, acc10, 0, 0, 0);
        acc11 = MFMA16(a1, b1, acc11, 0, 0, 0);
      }
      spin_flags(flag0, (unsigned)(t+1), lane);   // y0[t] + eps partials ready
      {
        const u64* ep = reinterpret_cast<const u64*>(epsP + (size_t)t*128);
        u64 v = AGLD(ep + lane);
        int s = (int)(unsigned)v + (int)(unsigned)(v >> 32);
        #pragma unroll
        for (int mm = 32; mm; mm >>= 1) s += __shfl_xor(s, mm);
        et = (float)s * 4.6566128730773926e-10f;  // / (2^16 * 32768)
      }
      const unsigned short* Ay = Ring0 + (size_t)t*32768 + l15*HID + koff;
      #pragma unroll 4
      for (int kt = 0; kt < 32; ++kt){
        bf16x8 a0 = ldA(Ay + kt*32);
        bf16x8 a1 = ldA(Ay + 16*HID + kt*32);
        bf16x8 b0 = lds_frag(ldsW, kt*2 + 0, lane);
        bf16x8 b1 = lds_frag(ldsW, kt*2 + 1, lane);
        acc00 = MFMA16(a0, b0, acc00, 0, 0, 0);
        acc01 = MFMA16(a0, b1, acc01, 0, 0, 0);
        acc10 = MFMA16(a1, b0, acc10, 0, 0, 0);
        acc11 = MFMA16(a1, b1, acc11, 0, 0, 0);
      }
    }

    // ---- epilogue: activations, c/h update, MINIMAL publish ----
    unsigned short* ring = L ? (Ring1 + (size_t)(t & 7)*32768) : (Ring0 + (size_t)t*32768);
    float hyv[2][4], ccv[2][4];
    float psum = 0.f;
    #pragma unroll
    for (int m = 0; m < 2; ++m){
      f32x4 ga = m ? acc10 : acc00;   // cols 0..7 = i, 8..15 = f
      f32x4 gb = m ? acc11 : acc01;   // cols 16..23 = g, 24..31 = o
      #pragma unroll
      for (int r = 0; r < 4; ++r){
        float g0 = ga[r] + bia0 + et*rsv0;
        float g1 = gb[r] + bia1 + et*rsv1;
        float p0 = __shfl_xor(g0, 8);
        float p1 = __shfl_xor(g1, 8);
        float iv = isLow ? g0 : p0;
        float fv = isLow ? p0 : g0;
        float gv = isLow ? g1 : p1;
        float ov = isLow ? p1 : g1;
        iv = fminf(fmaxf(0.2f*iv + 0.5f, 0.f), 1.f);
        fv = fminf(fmaxf(0.2f*fv + 0.5f, 0.f), 1.f);
        gv = fminf(fmaxf(gv, -1.f), 1.f);
        ov = fminf(fmaxf(0.2f*ov + 0.5f, 0.f), 1.f);
        float cc = fv*(creg[m][r] + et) + iv*gv;
        creg[m][r] = cc;
        float hy = ov * fminf(fmaxf(cc, -1.f), 1.f);
        hyv[m][r] = hy; ccv[m][r] = cc;

        unsigned short hu = f2bf(hy);
        unsigned p2 = (unsigned)hu | (((unsigned)__shfl_xor((int)hu, 1)) << 16);
        unsigned q2 = (unsigned)__shfl_xor((int)p2, 2);
        if (isLow){
          if (!(lane & 3)){
            int b = m*16 + bq + r;
            u64 w = (u64)p2 | ((u64)q2 << 32);          // 4 bf16, LLC write-through
            AGST(reinterpret_cast<u64*>(ring + b*HID + jw), w);
          }
          if (L == 0) psum += hy;
        }
      }
    }
    if (L == 0){
      #pragma unroll
      for (int mm = 32; mm; mm >>= 1) psum += __shfl_xor(psum, mm);
      if (lane == 0)
        AGST(reinterpret_cast<unsigned*>(epsP + (size_t)t*128 + bid),
             (unsigned)(int)llrintf(psum * 65536.f));
    }

    // drain ONLY ring/eps publishes, then flag — d_out stores come after
    asm volatile("s_waitcnt vmcnt(0)" ::: "memory");
    if (lane == 0) AGST(myflag, (unsigned)(t+1));

    // ---- off-critical-path stores (overlap next step's x-half / spin) ----
    if (L){
      #pragma unroll
      for (int m = 0; m < 2; ++m)
        #pragma unroll
        for (int r = 0; r < 4; ++r){
          float hy = hyv[m][r];
          float f1 = __shfl_xor(hy, 1);
          float f2 = __shfl_xor(hy, 2);
          float f3 = __shfl_xor(f1, 2);
          if (isLow && !(lane & 3)){
            int b = m*16 + bq + r;
            f32x4 o4 = {hy, f1, f2, f3};
            *reinterpret_cast<f32x4*>(out + (size_t)t*32768 + b*HID + jw) = o4;
          }
        }
    }
    if (t == T_STEPS-1){
      #pragma unroll
      for (int m = 0; m < 2; ++m)
        #pragma unroll
        for (int r = 0; r < 4; ++r)
          if (isLow){
            int b = m*16 + bq + r;
            outHn[b*HID + jw] = hyv[m][r];
            outCn[b*HID + jw] = ccv[m][r];
          }
    }
  }
}

// ---------------- host ----------------

extern "C" void kernel_launch(void* const* d_in, const int* in_sizes, int n_in,
                              void* d_out, int out_size, void* d_ws, size_t ws_size,
                              hipStream_t stream)
{
  const float* x    = (const float*)d_in[0];
  const float* h0   = (const float*)d_in[1];
  const float* c0   = (const float*)d_in[2];
  const float* Wih0 = (const float*)d_in[3];
  const float* Whh0 = (const float*)d_in[4];
  const float* bih0 = (const float*)d_in[5];
  const float* bhh0 = (const float*)d_in[6];
  const float* Wih1 = (const float*)d_in[7];
  const float* Whh1 = (const float*)d_in[8];
  const float* bih1 = (const float*)d_in[9];
  const float* bhh1 = (const float*)d_in[10];
  float* out = (float*)d_out;

  char* ws = (char*)d_ws;
  size_t off = 0;
  auto alloc = [&](size_t bytes)->char* {
    char* p = ws + off; off += (bytes + 255) & ~(size_t)255; return p;
  };
  unsigned short* Xbf   = (unsigned short*)alloc((size_t)T_STEPS*BATCH*HID*2); // 32MB
  unsigned short* Ring0 = (unsigned short*)alloc((size_t)T_STEPS*BATCH*HID*2); // 32MB
  unsigned short* Ring1 = (unsigned short*)alloc((size_t)8*BATCH*HID*2);
  unsigned short* Hini  = (unsigned short*)alloc((size_t)2*BATCH*HID*2);
  float* eps0 = (float*)alloc(T_STEPS*4);
  float* bias = (float*)alloc(2*4096*4);
  float* rs   = (float*)alloc(2*4096*4);
  int*   epsP = (int*)alloc((size_t)T_STEPS*128*4);   // fully rewritten each launch
  // per-launch-zeroed sync area: flag0 + flag1, 64 lines x 128B each
  char* sync = alloc(64*128*2);
  unsigned int* flag0 = (unsigned int*)sync;
  unsigned int* flag1 = (unsigned int*)(sync + 64*128);
  if (off > ws_size)
    fprintf(stderr, "HardLSTM: ws too small, need %zu have %zu\n", off, ws_size);

  hipMemsetAsync(sync, 0, 64*128*2, stream);
  prep_x<<<4096, 256, 0, stream>>>(x, Xbf, (T_STEPS*BATCH*HID)/8);
  reduce_mean_f32<<<T_STEPS, 256, 0, stream>>>(x, eps0, 1.0f);   // eps0 = mean(x_t)+1
  prep_rs<<<2048, 256, 0, stream>>>(Wih0, Whh0, Wih1, Whh1, bih0, bhh0, bih1, bhh1, rs, bias);
  prep_hinit<<<256, 256, 0, stream>>>(h0, Hini);

  rec_fused<<<256, 64, 0, stream>>>(Xbf, Hini, Ring0, Ring1, out,
      Wih0, Whh0, Wih1, Whh1, bias, rs, eps0, c0, flag0, flag1, epsP);
}